// Round 12
// baseline (841.997 us; speedup 1.0000x reference)
//
#include <hip/hip_runtime.h>

// Problem constants (from reference): T=1024, B=32, D=768, L=48
#define T_ 1024
#define B_ 32
#define D_ 768
#define L_ 48
#define TB_ (T_ * B_)   // 32768 rows of the emissions GEMM

typedef __attribute__((ext_vector_type(4))) float f32x4;

// ---------------------------------------------------------------------------
// Kernel A: E = exp(feats @ W + b)   (fp32, M=32768 N=48 K=768) — FROZEN
// (reg-staged, no global_load_lds).  (total - scan) has been 188-215 µs
// across five structurally different GEMMs; with the scan dropping to
// ~140 µs this round, emis_gemm must finally top the counter table and
// expose its own VALUBusy/Occupancy/FETCH for a counter-driven fix.
// ---------------------------------------------------------------------------
__global__ __launch_bounds__(128) void emis_gemm(
    const float* __restrict__ feats, const float* __restrict__ W,
    const float* __restrict__ bias, float* __restrict__ E) {
  __shared__ float fbuf[64 * 68];    // [row][k] padded +4
  __shared__ float wbuf[48 * 68];    // [j][ko] padded (2-way = free)
  const int tid = threadIdx.x;
  const int cg = tid & 7;            // col group -> cols c0..c0+5
  const int rg = tid >> 3;           // row group 0..15 -> rows rg+16i
  const int c0 = cg * 6;
  const int rowbase = blockIdx.x * 64;

  float acc[4][6];
#pragma unroll
  for (int i = 0; i < 4; i++)
#pragma unroll
    for (int c = 0; c < 6; c++) acc[i][c] = 0.f;

  for (int kc = 0; kc < D_; kc += 64) {
    __syncthreads();  // previous chunk's reads complete before overwrite

    // feats chunk 64x64: 8 float4 per thread, coalesced (16 lanes = one
    // 256B row segment), ds_write_b128 (rows 16B-aligned: stride 272B).
#pragma unroll
    for (int i = 0; i < 8; i++) {
      const int idx = tid + i * 128;   // 0..1023
      const int r = idx >> 4;          // 0..63
      const int ch = idx & 15;         // 0..15
      const float4 v =
          *(const float4*)(feats + (size_t)(rowbase + r) * D_ + kc + ch * 4);
      *(float4*)(fbuf + r * 68 + ch * 4) = v;
    }

    // W chunk transposed: wbuf[j][ko] = W[kc+ko][j] (coalesced reads)
#pragma unroll
    for (int i = 0; i < 24; i++) {
      const int idx = tid + i * 128;  // 0..3071
      const int ko = idx / 48;
      const int j = idx - ko * 48;
      wbuf[j * 68 + ko] = W[(kc + ko) * L_ + j];
    }

    __syncthreads();

#pragma unroll 4
    for (int k4 = 0; k4 < 16; k4++) {
      float4 fv[4];
      float4 wv4[6];
#pragma unroll
      for (int i = 0; i < 4; i++)
        fv[i] = *(const float4*)(fbuf + (rg + 16 * i) * 68 + k4 * 4);
#pragma unroll
      for (int cc = 0; cc < 6; cc++)
        wv4[cc] = *(const float4*)(wbuf + (c0 + cc) * 68 + k4 * 4);
#pragma unroll
      for (int i = 0; i < 4; i++) {
#pragma unroll
        for (int cc = 0; cc < 6; cc++) {
          acc[i][cc] = fmaf(fv[i].x, wv4[cc].x, acc[i][cc]);
          acc[i][cc] = fmaf(fv[i].y, wv4[cc].y, acc[i][cc]);
          acc[i][cc] = fmaf(fv[i].z, wv4[cc].z, acc[i][cc]);
          acc[i][cc] = fmaf(fv[i].w, wv4[cc].w, acc[i][cc]);
        }
      }
    }
  }

  // epilogue: E = exp(acc + bias), rows rg+16i, cols c0..c0+5
#pragma unroll
  for (int i = 0; i < 4; i++) {
    float* dst = E + (size_t)(rowbase + rg + 16 * i) * L_ + c0;
#pragma unroll
    for (int cc = 0; cc < 6; cc += 2) {
      float2 v;
      v.x = __expf(acc[i][cc + 0] + bias[c0 + cc + 0]);
      v.y = __expf(acc[i][cc + 1] + bias[c0 + cc + 1]);
      *(float2*)(dst + cc) = v;
    }
  }
}

// ---------------------------------------------------------------------------
// Kernel B: ONE WAVE PER BLOCK, one pass per block (grid = 2*B = 64 blocks
// <= 256 CUs -> 1 wave/CU, private DS pipe).  Scaled-probability recurrence.
//
// Register-grant evidence: plain launch_bounds targets MAX OCCUPANCY (8
// waves/SIMD -> 64-VGPR budget) and spills (R11: grant 60 vs ~78 demand ->
// 650 cyc/step, P spilled AND broadcast reads serialized for lack of
// in-flight destination regs).  amdgpu_waves_per_eu ONE-ARG sets only the
// MIN (no-op, R8).  The TWO-ARG form (1,1) sets MAX waves/EU = 1: the
// allocator loses its occupancy incentive, budget -> 512 VGPRs, so P[48] +
// all 12 in-flight b128 read-destinations + prefetch fit with ZERO spills.
// Occupancy is irrelevant: 64 single-wave blocks = 1 wave/CU either way.
//
// Per step: 1 stride-1 ds_write_b32 publish + 12 broadcast ds_read_b128
// (conflict-free, fully pipelined) + 48 FMAs in 4 chains: ~300-350 cyc.
//   - tags folded into emissions at load (ev_eff = tg ? 0 : E[..]); since
//     u = sum * evp, a zero emission zeroes u identically -> no per-step
//     selects, no tag registers.
//   - rescale (t%8==1) zero-cross-lane: m = max over the same broadcast
//     state reads (lane-uniform by construction), folded into the step's
//     emission multiply; logacc += log(m).  Worst unscaled stretch <= 11
//     steps, far inside fp32 range.
//   - combine: atomicAdd(out+b, +/-logZ): exactly 2 commutative adds.
// Parity: state(t) lives in sbuf[t&1]; the step producing state t reads
// (t-1)&1, writes t&1.  2-step bodies keep t odd; tail <= 1 step.
// ---------------------------------------------------------------------------
__global__ __launch_bounds__(64)
__attribute__((amdgpu_waves_per_eu(1, 1))) void crf_scan(
    const float* __restrict__ E, const int* __restrict__ tags,
    const int* __restrict__ lens, const float* __restrict__ begin,
    const float* __restrict__ trans, const float* __restrict__ endt,
    const int* __restrict__ bc, const int* __restrict__ ec,
    const int* __restrict__ tc, float* __restrict__ out) {
  __shared__ __align__(16) float sbuf[2][64];   // [parity][slot]
  const int s = blockIdx.x;
  const int pass = s & 1;   // 0 = unconstrained fwd, 1 = constrained partial
  const int b = s >> 1;
  const int lane = threadIdx.x;
  const bool act = lane < L_;
  const bool par = (pass == 1);
  const int len = lens[b];            // in [512, 1024]
  const int stride = B_ * L_;
  const int base = b * L_ + (act ? lane : 0);  // clamped for lanes 48..63

  // Transition row fully in registers: P[k] = exp(trans[lane][k]); zero for
  // inactive lanes; constraint-masked on the partial pass.
  float P[L_];
#pragma unroll
  for (int k = 0; k < L_; k++) {
    float v = 0.f;
    if (act) {
      v = __expf(trans[lane * L_ + k]);
      if (par && tc[lane * L_ + k]) v = 0.f;
    }
    P[k] = v;
  }

  // emission load with tag fold (partial pass only)
  auto loadE = [&](int tt) -> float {
    float ev = E[(size_t)tt * stride + base];
    if (par && tags[(size_t)tt * stride + base]) ev = 0.f;
    return ev;
  };

  // init: a0 = E[0]*exp(begin); partial pass additionally masked by bc/tags
  float a = 0.f;
  if (act) {
    a = E[base] * __expf(begin[lane]);
    if (par && (bc[lane] || tags[base])) a = 0.f;
  }
  float logacc = 0.f;

  sbuf[0][lane] = a;  // state(t=0) -> parity 0

  // Step producing state t (par_in = (t-1)&1).  resc: normalize by m = max
  // of the input state (from the same broadcast reads; lane-uniform).
  auto step = [&](int par_in, float ev, bool resc) {
    const f32x4* src = (const f32x4*)sbuf[par_in];
    float s0 = 0.f, s1 = 0.f, s2 = 0.f, s3 = 0.f;
    f32x4 mx = {0.f, 0.f, 0.f, 0.f};  // state is non-negative
#pragma unroll
    for (int c = 0; c < 12; c++) {
      const f32x4 q = src[c];  // broadcast read: all lanes same address
      if (resc) {
        mx.x = fmaxf(mx.x, q.x);
        mx.y = fmaxf(mx.y, q.y);
        mx.z = fmaxf(mx.z, q.z);
        mx.w = fmaxf(mx.w, q.w);
      }
      s0 = fmaf(q.x, P[4 * c + 0], s0);
      s1 = fmaf(q.y, P[4 * c + 1], s1);
      s2 = fmaf(q.z, P[4 * c + 2], s2);
      s3 = fmaf(q.w, P[4 * c + 3], s3);
    }
    float evp = ev;
    if (resc) {
      float m = fmaxf(fmaxf(mx.x, mx.y), fmaxf(mx.z, mx.w));
      m = fmaxf(m, 1e-30f);     // uniform across lanes (same broadcast data)
      logacc += __logf(m);
      evp = ev * (1.f / m);
    }
    const float u = ((s0 + s1) + (s2 + s3)) * evp;
    a = u;
    sbuf[par_in ^ 1][lane] = u;  // publish for the next step
  };

  // preload tag-folded emissions for t = 1, 2 (len >= 512 so always valid)
  float e2[2] = {loadE(1), loadE(2)};

  int t = 1;  // bodies keep t odd; rescale when t == 1 (mod 8)
  for (; t + 2 <= len; t += 2) {
    int t2 = t + 2, t3 = t + 3;
    t2 = (t2 < len) ? t2 : (len - 1);
    t3 = (t3 < len) ? t3 : (len - 1);
    const float p0 = loadE(t2);
    const float p1 = loadE(t3);
    if ((t & 7) == 1) {
      step(0, e2[0], true);   // t odd -> input parity 0
    } else {
      step(0, e2[0], false);
    }
    step(1, e2[1], false);    // state t+1, input parity 1
    e2[0] = p0;
    e2[1] = p1;
  }
  // tail: one step iff t < len (t odd -> input parity 0)
  if (t < len) step(0, e2[0], false);

  // readout: logZ = logacc + log(sum_j a[j]*exp(end[j]))
  float z = 0.f;
  if (act) {
    float ez = __expf(endt[lane]);
    if (par && ec[lane]) ez = 0.f;
    z = a * ez;
  }
#pragma unroll
  for (int off = 32; off; off >>= 1) z += __shfl_xor(z, off, 64);
  const float logZ = logacc + __logf(z);
  if (lane == 0) atomicAdd(out + b, par ? -logZ : logZ);
}

// ---------------------------------------------------------------------------
extern "C" void kernel_launch(void* const* d_in, const int* in_sizes, int n_in,
                              void* d_out, int out_size, void* d_ws,
                              size_t ws_size, hipStream_t stream) {
  (void)in_sizes; (void)n_in; (void)out_size; (void)ws_size;
  const float* feats = (const float*)d_in[0];
  const int* tags = (const int*)d_in[1];
  const int* lens = (const int*)d_in[2];
  const float* W = (const float*)d_in[3];
  const float* bias = (const float*)d_in[4];
  const float* begin = (const float*)d_in[5];
  const float* trans = (const float*)d_in[6];
  const float* endt = (const float*)d_in[7];
  const int* bc = (const int*)d_in[8];
  const int* ec = (const int*)d_in[9];
  const int* tc = (const int*)d_in[10];

  float* E = (float*)d_ws;  // T*B*L floats = 6 MB scratch, exp(emissions)
  float* out = (float*)d_out;

  hipMemsetAsync(d_out, 0, B_ * sizeof(float), stream);

  emis_gemm<<<dim3(TB_ / 64), dim3(128), 0, stream>>>(feats, W, bias, E);
  crf_scan<<<dim3(2 * B_), dim3(64), 0, stream>>>(E, tags, lens, begin, trans,
                                                  endt, bc, ec, tc, out);
}